// Round 8
// baseline (201.308 us; speedup 1.0000x reference)
//
#include <hip/hip_runtime.h>

#define B_ 8
#define C_ 256
#define CQ_ 32
#define N_ 4096

typedef __attribute__((ext_vector_type(8))) short short8;
typedef __attribute__((ext_vector_type(4))) float float4v;

// log2(e) / sqrt(32): folded into q so softmax uses exp2
#define QSCALE 0.2550599232f

#if __has_builtin(__builtin_amdgcn_exp2f)
#define EXP2F __builtin_amdgcn_exp2f
#else
#define EXP2F exp2f
#endif

static __device__ __forceinline__ unsigned short f2bf(float f) {
  unsigned int u = __float_as_uint(f);
  u += 0x7FFFu + ((u >> 16) & 1u);   // RNE
  return (unsigned short)(u >> 16);
}

// pack two floats to bf16x2 (same RNE as f2bf -> bit-identical)
static __device__ __forceinline__ unsigned int pk2bf(float a, float b) {
  return (unsigned int)f2bf(a) | ((unsigned int)f2bf(b) << 16);
}

// async 16B/lane global->LDS DMA (dest = wave-uniform base + lane*16)
static __device__ __forceinline__ void async16(void* lds, const void* g) {
  __builtin_amdgcn_global_load_lds(
      (const __attribute__((address_space(1))) unsigned int*)g,
      (__attribute__((address_space(3))) unsigned int*)lds, 16, 0, 0);
}

// ---------------- W fp32 -> bf16 (q rows pre-scaled by QSCALE) ----------------
__global__ __launch_bounds__(256) void wconv_kernel(
    const float* __restrict__ wq, const float* __restrict__ wk,
    const float* __restrict__ wv, unsigned short* __restrict__ w_bf) {
  int o = blockIdx.x * 8 + (threadIdx.x >> 5);
  int c8 = (threadIdx.x & 31) * 8;
  const float* src; float sc = 1.f;
  if (o < 32)      { src = wq + (size_t)o * 256; sc = QSCALE; }
  else if (o < 64) { src = wk + (size_t)(o - 32) * 256; }
  else             { src = wv + (size_t)(o - 64) * 256; }
  float4 a = *(const float4*)(src + c8);
  float4 bq = *(const float4*)(src + c8 + 4);
  unsigned short t[8] = {f2bf(a.x*sc), f2bf(a.y*sc), f2bf(a.z*sc), f2bf(a.w*sc),
                         f2bf(bq.x*sc), f2bf(bq.y*sc), f2bf(bq.z*sc), f2bf(bq.w*sc)};
  *(uint4*)(w_bf + (size_t)o * 256 + c8) = *(const uint4*)t;
}

// ---------------- fused convert+projection: q/k/v = W @ x ----------------
// v7 structure (async-split). proj+wconv measured residual is mostly
// harness overhead (~17 reset dispatches/iter, dispatch-ID arithmetic);
// two consecutive proj rewrites produced zero total delta -> FROZEN.
__global__ __launch_bounds__(256, 2) void proj_kernel(
    const float* __restrict__ x, const unsigned short* __restrict__ w_bf,
    unsigned short* __restrict__ qT, unsigned short* __restrict__ kT,
    unsigned short* __restrict__ v) {
  __shared__ __align__(16) unsigned short xb[2][64 * 32];
  int tid = threadIdx.x, wave = tid >> 6, lane = tid & 63;
  int q16 = lane >> 4, l16 = lane & 15;
  int b = blockIdx.x, n0 = blockIdx.y * 64;

  int p = tid & 15, n4g = tid >> 4;
  const float* x0 = x + (size_t)b * C_ * N_ + n0 + n4g * 4;

  float4 xra, xrb;  // in-flight x rows (registers)
  auto xload = [&](int ks) {
    const float* r0 = x0 + (size_t)(ks * 32 + 2 * p) * N_;
    xra = *(const float4*)(r0);
    xrb = *(const float4*)(r0 + N_);
  };
  auto xwrite = [&](int buf) {
    float va[4] = {xra.x, xra.y, xra.z, xra.w};
    float vb[4] = {xrb.x, xrb.y, xrb.z, xrb.w};
    #pragma unroll
    for (int i = 0; i < 4; ++i) {
      int n = n4g * 4 + i;
      unsigned int pk = pk2bf(va[i], vb[i]);
      int so = (p >> 2) ^ ((n >> 1) & 3);
      *(unsigned int*)(&xb[buf][n * 32 + so * 8 + (p & 3) * 2]) = pk;
    }
  };

  int o0 = wave * 80;
  auto afload = [&](short8* dst, int ks) {
    #pragma unroll
    for (int mt = 0; mt < 5; ++mt)
      dst[mt] = *(const short8*)(w_bf + (size_t)(o0 + mt * 16 + l16) * 256 + ks * 32 + q16 * 8);
  };

  float4v acc[5][4];
  float4v zerov = {0.f, 0.f, 0.f, 0.f};
  #pragma unroll
  for (int mt = 0; mt < 5; ++mt)
    for (int nt = 0; nt < 4; ++nt) acc[mt][nt] = zerov;

  short8 afc[5], afn[5];
  xload(0);
  afload(afc, 0);
  xwrite(0);
  __syncthreads();

  int sxo = (q16 ^ ((l16 >> 1) & 3)) * 8;
  #pragma unroll 1
  for (int ks = 0; ks < 8; ++ks) {
    if (ks < 7) {
      xload(ks + 1);
      afload(afn, ks + 1);
    }
    short8 bf4[4];
    #pragma unroll
    for (int nt = 0; nt < 4; ++nt)
      bf4[nt] = *(const short8*)(&xb[ks & 1][(nt * 16 + l16) * 32 + sxo]);
    #pragma unroll
    for (int mt = 0; mt < 5; ++mt)
      #pragma unroll
      for (int nt = 0; nt < 4; ++nt)
        acc[mt][nt] = __builtin_amdgcn_mfma_f32_16x16x32_bf16(afc[mt], bf4[nt], acc[mt][nt], 0, 0, 0);
    if (ks < 7) {
      xwrite((ks + 1) & 1);
      #pragma unroll
      for (int mt = 0; mt < 5; ++mt) afc[mt] = afn[mt];
    }
    __syncthreads();
  }

  #pragma unroll
  for (int mt = 0; mt < 5; ++mt) {
    int og = o0 + mt * 16 + q16 * 4;
    #pragma unroll
    for (int nt = 0; nt < 4; ++nt) {
      int n = n0 + nt * 16 + l16;
      if (og < 64) {
        unsigned short t[4];
        #pragma unroll
        for (int r = 0; r < 4; ++r) t[r] = f2bf(acc[mt][nt][r]);
        unsigned short* dst = (og < 32) ? (qT + ((size_t)b * N_ + n) * CQ_ + og)
                                        : (kT + ((size_t)b * N_ + n) * CQ_ + (og - 32));
        *(uint2*)dst = *(const uint2*)t;
      } else {
        // ---- v tile: 4x4 transpose across lane quads (reg <-> lane&3) ----
        float a[4] = {acc[mt][nt][0], acc[mt][nt][1], acc[mt][nt][2], acc[mt][nt][3]};
        #pragma unroll
        for (int m = 1; m <= 2; m <<= 1) {
          float t[4];
          #pragma unroll
          for (int r = 0; r < 4; ++r) t[r] = __shfl_xor(a[r ^ m], m);
          #pragma unroll
          for (int r = 0; r < 4; ++r)
            if ((lane ^ r) & m) a[r] = t[r];
        }
        uint2 w;
        w.x = pk2bf(a[0], a[1]);
        w.y = pk2bf(a[2], a[3]);
        int ch = og - 64 + (l16 & 3);
        int nn = n0 + nt * 16 + (l16 & 12);
        *(uint2*)(v + ((size_t)b * C_ + ch) * N_ + nn) = w;
      }
    }
  }
}

// ---------------- Flash attention + residual (v8: M=64, 2 blocks/CU) ----------------
// Schedule = v1/v6 EXACTLY (proven best of 7 variants), but block halved:
// M=64 queries, 4 waves (256 thr), grid 512 (b = bid&7 XCD-pin, m0 =
// (bid>>3)*64) -> TWO independent blocks per CU (LDS 48.3KB x2 = 97KB).
// One block's compute fills the other's barrier drains (the ~40% lockstep
// stall that 6 schedule rewrites could not remove at 1 block/CU).
// Cost: V/K DMA per unit work doubles (V is XCD-L2-resident, no HBM delta).
// Wave remap only; all layouts/swizzles/numerics identical to v6:
//   S/softmax: wave w owns queries w*16..+15 (of the block's 64).
//   PV: wave w owns channel quarter w (64 ch) x all 64 q.
//   stageV: each wave stages 64 ch (8 instrs); stageK: all 4 waves, 16 rows each.
__global__ __launch_bounds__(256, 2) void attn_kernel(
    const unsigned short* __restrict__ qT, const unsigned short* __restrict__ kT,
    const unsigned short* __restrict__ v, const float* __restrict__ x,
    const float* __restrict__ gamma, float* __restrict__ out) {
  __shared__ __align__(16) unsigned short v_lds[256 * 64];     // 32 KB
  __shared__ __align__(16) unsigned short kt_lds[2][64 * 32];  // 2 x 4 KB
  __shared__ __align__(16) unsigned short p_lds[64 * 64];      // 8 KB
  __shared__ float l_lds[64];

  int tid = threadIdx.x, wave = tid >> 6, lane = tid & 63;
  int q16 = lane >> 4, l16 = lane & 15;
  int bid = blockIdx.x, b = bid & 7, m0 = (bid >> 3) * 64;

  short8 qfrag = *(const short8*)(qT + ((size_t)b * N_ + m0 + wave * 16 + l16) * CQ_ + q16 * 8);

  const unsigned short* vbase = v + (size_t)b * C_ * N_;
  // stageV: 4 waves, 8 instrs each; rows 8/instr, phys octet = logical ^ (row&7)
  auto stageV = [&](int j0) {
    #pragma unroll
    for (int it = 0; it < 8; ++it) {
      int r = wave * 64 + it * 8 + (lane >> 3);
      int lo = (lane & 7) ^ (lane >> 3);
      async16(&v_lds[(wave * 64 + it * 8) * 64], vbase + (size_t)r * N_ + j0 + lo * 8);
    }
  };
  // stageK: all 4 waves, 1 instr each (16 rows/wave); phys octet = logical ^ ((row>>1)&3)
  auto stageK = [&](int buf, int j0) {
    int r = wave * 16 + (lane >> 2);
    int lo = (lane & 3) ^ ((r >> 1) & 3);
    async16(&kt_lds[buf][wave * 16 * 32], kT + ((size_t)b * N_ + j0 + r) * CQ_ + lo * 8);
  };

  stageK(0, 0);
  stageV(0);
  __syncthreads();

  float4v acc[4][4];  // [mt (16-q tile of the block's 64 q)][ct (16-c tile of wave's 64-c quarter)]
  float4v zerov = {0.f, 0.f, 0.f, 0.f};
  #pragma unroll
  for (int mt = 0; mt < 4; ++mt)
    for (int ct = 0; ct < 4; ++ct) acc[mt][ct] = zerov;
  float lrun = 0.f;

  int kro = q16 ^ ((l16 >> 1) & 3);
  int vro = l16 & 7;
  int cq = wave;

  // P-store bases (swapped layout): row = q = wave*16 + l16
  unsigned short* prow_base = &p_lds[(wave * 16 + l16) * 64];
  int rl = l16 & 7;
  int halfsel = (q16 & 1) * 4;
  int hoct = q16 >> 1;

  for (int j = 0; j < 64; ++j) {
    int cur = j & 1;
    // ---- S^T = K.Q^T : wave's 64 keys x 16 q (swapped operands) ----
    float4v s[4];
    #pragma unroll
    for (int jt = 0; jt < 4; ++jt) {
      short8 kf = *(const short8*)(&kt_lds[cur][(jt * 16 + l16) * 32 + kro * 8]);
      s[jt] = __builtin_amdgcn_mfma_f32_16x16x32_bf16(kf, qfrag, zerov, 0, 0, 0);
    }

    // ---- softmax-lite + packed P-store (4x ds_write_b64) ----
    #pragma unroll
    for (int jt = 0; jt < 4; ++jt) {
      float e0 = EXP2F(s[jt][0]), e1 = EXP2F(s[jt][1]);
      float e2 = EXP2F(s[jt][2]), e3 = EXP2F(s[jt][3]);
      lrun += (e0 + e1) + (e2 + e3);
      uint2 w;
      w.x = pk2bf(e0, e1);
      w.y = pk2bf(e2, e3);
      int physO = (jt * 2 + hoct) ^ rl;   // logical octet ^ (row&7)
      *(uint2*)(prow_base + physO * 8 + halfsel) = w;
    }
    if (j == 63) {
      float t = lrun;
      t += __shfl_xor(t, 16);
      t += __shfl_xor(t, 32);
      if (lane < 16) l_lds[wave * 16 + l16] = t;
    }
    __syncthreads();  // A: P visible; V(j)/kt(j) DMA drained

    if (j < 63) stageK(cur ^ 1, (j + 1) * 64);  // overlaps PV, drained at B

    // ---- PV: all 64 q x wave's 64 c (quarter cq) ----
    #pragma unroll
    for (int ks = 0; ks < 2; ++ks) {
      short8 pf[4], vf[4];
      #pragma unroll
      for (int mt = 0; mt < 4; ++mt)
        pf[mt] = *(const short8*)(&p_lds[(mt * 16 + l16) * 64 + ((ks * 4 + q16) ^ vro) * 8]);
      #pragma unroll
      for (int ct = 0; ct < 4; ++ct)
        vf[ct] = *(const short8*)(&v_lds[(cq * 64 + ct * 16 + l16) * 64 + ((ks * 4 + q16) ^ vro) * 8]);
      #pragma unroll
      for (int mt = 0; mt < 4; ++mt)
        #pragma unroll
        for (int ct = 0; ct < 4; ++ct)
          acc[mt][ct] = __builtin_amdgcn_mfma_f32_16x16x32_bf16(pf[mt], vf[ct], acc[mt][ct], 0, 0, 0);
    }
    __syncthreads();  // B: PV reads done; kt(j+1) drained

    if (j < 63) stageV((j + 1) * 64);  // drained at next A; hidden by S+softmax
  }

  // ---- epilogue: out = gamma * O/l + x ----
  float g = gamma[0];
  #pragma unroll
  for (int mt = 0; mt < 4; ++mt) {
    float linv[4];
    #pragma unroll
    for (int r = 0; r < 4; ++r) linv[r] = 1.f / l_lds[mt * 16 + q16 * 4 + r];
    int n = m0 + mt * 16 + q16 * 4;
    #pragma unroll
    for (int ct = 0; ct < 4; ++ct) {
      int c = cq * 64 + ct * 16 + l16;
      size_t off = ((size_t)b * C_ + c) * N_ + n;
      float4 xv = *(const float4*)(x + off);
      float4 o;
      o.x = g * acc[mt][ct][0] * linv[0] + xv.x;
      o.y = g * acc[mt][ct][1] * linv[1] + xv.y;
      o.z = g * acc[mt][ct][2] * linv[2] + xv.z;
      o.w = g * acc[mt][ct][3] * linv[3] + xv.w;
      *(float4*)(out + off) = o;
    }
  }
}

extern "C" void kernel_launch(void* const* d_in, const int* in_sizes, int n_in,
                              void* d_out, int out_size, void* d_ws, size_t ws_size,
                              hipStream_t stream) {
  const float* x     = (const float*)d_in[0];
  const float* wq    = (const float*)d_in[1];
  const float* wk    = (const float*)d_in[2];
  const float* wv    = (const float*)d_in[3];
  const float* gamma = (const float*)d_in[4];
  float* out = (float*)d_out;

  unsigned short* qT  = (unsigned short*)d_ws;                  // 2 MB
  unsigned short* kT  = qT + (size_t)B_ * N_ * CQ_;             // 2 MB
  unsigned short* vv  = kT + (size_t)B_ * N_ * CQ_;             // 16.8 MB
  unsigned short* wbf = vv + (size_t)B_ * C_ * N_;              // 160 KB

  hipLaunchKernelGGL(wconv_kernel, dim3(40), dim3(256), 0, stream, wq, wk, wv, wbf);
  hipLaunchKernelGGL(proj_kernel, dim3(8, 64), dim3(256), 0, stream, x, wbf, qT, kT, vv);
  hipLaunchKernelGGL(attn_kernel, dim3(512), dim3(256), 0, stream, qT, kT, vv, x, gamma, out);
}